// Round 12
// baseline (63.057 us; speedup 1.0000x reference)
//
#include <hip/hip_runtime.h>
#include <hip/hip_bf16.h>
#include <math.h>

// Problem constants
#define U_   300
#define K_   19
#define FC_  100
#define B_   256
#define L_   1000
#define P_   140     // pooled length
#define EPS_ 1e-5f
#define WLD_ 144     // fc LDS row stride (bf16): 288 B, 16-B aligned

typedef unsigned short ushort_t;
typedef __attribute__((ext_vector_type(8)))  short short8v;   // 8 bf16 = 4 VGPR
typedef __attribute__((ext_vector_type(16))) float f32x16;    // MFMA 32x32 acc

// f32 -> bf16 round-to-nearest-even (bit trick)
__device__ __forceinline__ ushort_t f2bf(float f) {
    union { float f; unsigned u; } a; a.f = f;
    unsigned r = a.u + 0x7fffu + ((a.u >> 16) & 1u);
    return (ushort_t)(r >> 16);
}

// ---------------------------------------------------------------------------
// pack_conv_k: conv weights -> bf16, BN1 scale folded, COALESCED-TILE layout:
//   element offset = nt*2560 + kc*512 + r*16 + half*8 + e
// where u = nt*32 + r, j(=GEMM k, order 4*t+d) = kc*16 + half*8 + e.
// A wave's B-frag load (fixed kc) is then 64 lanes x 16 B contiguous = 2 KB.
// o1g padded to 320.
// ---------------------------------------------------------------------------
__global__ __launch_bounds__(256, 4)
void pack_conv_k(const float* __restrict__ w_conv, const float* __restrict__ b_conv,
                 const float* __restrict__ g1, const float* __restrict__ be1,
                 const float* __restrict__ m1, const float* __restrict__ v1,
                 ushort_t* __restrict__ w_bf, float* __restrict__ o1g)
{
    const int t = blockIdx.x * 256 + threadIdx.x;
    if (t < 320 * 80) {
        const int u = t / 80, j = t - u * 80;
        float val = 0.f;
        if (u < U_ && j < 76) {
            const int tp = j >> 2;          // kernel position 0..18
            const int d  = j & 3;           // DNA channel 0..3
            const float s1 = g1[u] / sqrtf(v1[u] + EPS_);
            val = w_conv[u * 76 + 19 * d + tp] * s1;
        }
        const int nt = u >> 5, r = u & 31;
        const int kc = j >> 4, rem = j & 15;
        w_bf[nt * 2560 + kc * 512 + r * 16 + rem] = f2bf(val);
    }
    if (t < 320) {
        float o = 0.f;
        if (t < U_) {
            const float s1 = g1[t] / sqrtf(v1[t] + EPS_);
            o = (b_conv[t] - m1[t]) * s1 + be1[t];
        }
        o1g[t] = o;
    }
}

// ---------------------------------------------------------------------------
// conv_mfma_k: implicit-GEMM conv + BN1 + maxpool + exp, pooling IN REGISTERS.
// 896 threads = 14 waves: wave wv -> (m-tile mt = wv%7, nt-half = wv/7).
// Each wave: 5 nt-iterations (halved serial path); 2 blocks/CU -> 28 waves/CU.
// Block covers 28 windows (5 blocks x 28 = 140 exact). A-fragments hoisted
// once; B-fragments (coalesced layout) + o1 double-buffered.
// Staging: GEMM rows 0..199 read x4 rows l..l+18 -> stage 220 rows.
// Per-tile row permutation puts two complete 7-row pool windows in each
// lane-half's C slots; window max = fmax over acc regs; one barrier.
// ---------------------------------------------------------------------------
__global__ __launch_bounds__(896, 7)
void conv_mfma_k(const float4* __restrict__ x4,        // (B,1000) float4 (D=4)
                 const ushort_t* __restrict__ w_bf,    // packed tiles (see pack)
                 const float* __restrict__ o1g,        // (320)
                 ushort_t* __restrict__ pooled)        // (U,B,P) bf16
{
    __shared__ ushort_t xls[880];        // bf16 x_flat rows l0..l0+219
    const int tid = threadIdx.x;
    const int b   = blockIdx.y;
    const int bx  = blockIdx.x;          // 0..4
    const int w0  = bx * 28;             // first window of block
    const int l0  = w0 * 7;              // first conv row (bx*196, max 784)

    if (tid < 220) {
        const int gi = l0 + tid;
        float4 v = make_float4(0.f, 0.f, 0.f, 0.f);
        if (gi < L_) v = x4[(size_t)b * L_ + gi];
        ushort4 pk;
        pk.x = f2bf(v.x); pk.y = f2bf(v.y); pk.z = f2bf(v.z); pk.w = f2bf(v.w);
        *(ushort4*)&xls[4 * tid] = pk;
    }
    __syncthreads();

    const int lane = tid & 63;
    const int wv   = tid >> 6;           // 0..13
    const int mt   = (wv < 7) ? wv : wv - 7;   // m-tile 0..6
    const int nth  = (wv < 7) ? 0 : 1;         // nt-half
    const int half = lane >> 5;
    const int r32  = lane & 31;

    // permuted A-row offset for slot r32
    const int sreg = (r32 & 3) + 4 * (r32 >> 3);
    const int sh   = (r32 >> 2) & 1;
    const int off  = sreg < 7  ? sreg + 7 * sh
                   : sreg < 14 ? sreg + 7 + 7 * sh
                               : 28 + (sreg - 14) + 2 * sh;

    const char* xb = (const char*)xls + 8 * (28 * mt + off) + 16 * half;
    // coalesced B base for this lane (element offset r32*16 + half*8)
    const char* wbase = (const char*)w_bf + 32 * r32 + 16 * half;

    // hoist nt-invariant A-fragments into registers
    short8v aA[5];
#pragma unroll
    for (int kc = 0; kc < 5; ++kc)
        aA[kc] = *(const short8v*)(xb + 32 * kc);

    const int pA = w0 + 4 * mt;          // window base of this tile (<=136)
    const int nt0 = nth * 5;

    // B-frag + o1 double buffer (first tile of this wave's half)
    short8v bfr[5];
#pragma unroll
    for (int kc = 0; kc < 5; ++kc)
        bfr[kc] = *(const short8v*)(wbase + nt0 * 5120 + 1024 * kc);
    float o1u = o1g[nt0 * 32 + r32];

    for (int i = 0; i < 5; ++i) {
        const int nt  = nt0 + i;
        const int ntn = (i < 4) ? nt + 1 : nt;      // dummy reload on last iter
        short8v bnx[5];
        const char* wn = wbase + ntn * 5120;
#pragma unroll
        for (int kc = 0; kc < 5; ++kc)
            bnx[kc] = *(const short8v*)(wn + 1024 * kc);
        const float o1n = o1g[ntn * 32 + r32];

        f32x16 acc = {};
#pragma unroll
        for (int kc = 0; kc < 5; ++kc)
            acc = __builtin_amdgcn_mfma_f32_32x32x16_bf16(aA[kc], bfr[kc], acc, 0, 0, 0);

        // in-register pooling (o1 added after max; exp monotone)
        float m0 = acc[0], m1 = acc[7];
#pragma unroll
        for (int j = 1; j < 7; ++j)  m0 = fmaxf(m0, acc[j]);
#pragma unroll
        for (int j = 8; j < 14; ++j) m1 = fmaxf(m1, acc[j]);
        const unsigned pk = (unsigned)f2bf(__expf(m0 + o1u)) |
                            ((unsigned)f2bf(__expf(m1 + o1u)) << 16);
        const unsigned ot = __shfl_xor(pk, 32);

        const int u = nt * 32 + r32;
        if (u < U_ && half == 0) {       // windows pA..pA+3 (pA+3 <= 139 always)
            ushort4 st;
            st.x = (ushort_t)(pk & 0xffff);   // p+0 (own m0)
            st.y = (ushort_t)(ot & 0xffff);   // p+1 (other m0)
            st.z = (ushort_t)(pk >> 16);      // p+2 (own m1)
            st.w = (ushort_t)(ot >> 16);      // p+3 (other m1)
            *(ushort4*)&pooled[((size_t)u * B_ + b) * P_ + pA] = st;
        }

#pragma unroll
        for (int kc = 0; kc < 5; ++kc) bfr[kc] = bnx[kc];
        o1u = o1n;
    }
}

// ---------------------------------------------------------------------------
// fc_mfma_k: per-unit FC1 via MFMA + BN2+ReLU+FC2+BN3+ReLU -> zT (B,304)
// Grid (2 bt, 300 u); 4 waves = 4 m-tiles (32 batches each) x all 4 n-tiles.
// B-operand: raw w_fc1 f32 panel staged ONCE per block into LDS as bf16
// (UNSCALED); BN2 scale s2 applied in the f32 epilogue (same math).
// ---------------------------------------------------------------------------
__global__ __launch_bounds__(256, 3)
void fc_mfma_k(const ushort_t* __restrict__ pooled,  // (U,B,P) bf16
               const float* __restrict__ w_fc1,      // (U,FC,P) f32
               const float* __restrict__ b_fc1,
               const float* __restrict__ g2,
               const float* __restrict__ be2,
               const float* __restrict__ m2,
               const float* __restrict__ v2,
               const float* __restrict__ w_fc2,
               const float* __restrict__ b_fc2,
               const float* __restrict__ g3,
               const float* __restrict__ be3,
               const float* __restrict__ m3,
               const float* __restrict__ v3,
               float* __restrict__ zT)               // (B,304)
{
    __shared__ ushort_t wlds[FC_ * WLD_];  // 100 rows x 144 bf16 = 28.8 KB
    __shared__ float zred[128][33];
    const int tid  = threadIdx.x;
    const int u    = blockIdx.y;
    const int bt   = blockIdx.x;          // 0/1 -> batches bt*128..+127

    // stage raw w_fc1 panel -> bf16 LDS (coalesced float4 reads)
    const float* __restrict__ wsrc = w_fc1 + (size_t)u * FC_ * P_;
    for (int idx = tid; idx < FC_ * 35; idx += 256) {
        const int f = idx / 35, j = idx - f * 35;
        const float4 v = *(const float4*)(wsrc + f * P_ + 4 * j);
        ushort4 pk;
        pk.x = f2bf(v.x); pk.y = f2bf(v.y); pk.z = f2bf(v.z); pk.w = f2bf(v.w);
        *(ushort4*)&wlds[f * WLD_ + 4 * j] = pk;
    }
    for (int idx = tid; idx < FC_ * 4; idx += 256) {
        const int f = idx >> 2, k = 140 + (idx & 3);
        wlds[f * WLD_ + k] = 0;
    }
    __syncthreads();

    const int lane = tid & 63;
    const int wv   = tid >> 6;            // m-tile within the 128-batch panel
    const int half = lane >> 5;
    const int r32  = lane & 31;

    const int brow = bt * 128 + wv * 32 + r32;
    const ushort_t* __restrict__ abase =
        pooled + ((size_t)u * B_ + brow) * P_ + half * 8;

    const ushort_t* __restrict__ bl0 = &wlds[r32 * WLD_ + half * 8];
    const ushort_t* __restrict__ bl1 = &wlds[(32 + r32) * WLD_ + half * 8];
    const ushort_t* __restrict__ bl2 = &wlds[(64 + r32) * WLD_ + half * 8];
    const int f3c = (96 + r32 < FC_) ? (96 + r32) : (FC_ - 1);   // clamp
    const ushort_t* __restrict__ bl3 = &wlds[f3c * WLD_ + half * 8];

    // A software-pipelined; B from LDS (low latency)
    short8v ac = *(const short8v*)(abase);
    f32x16 acc0 = {}, acc1 = {}, acc2 = {}, acc3 = {};
#pragma unroll
    for (int kc = 0; kc < 9; ++kc) {
        const int kn = (kc < 8) ? kc + 1 : kc;
        const short8v an = *(const short8v*)(abase + kn * 16);
        const short8v b0 = *(const short8v*)(bl0 + kc * 16);
        const short8v b1 = *(const short8v*)(bl1 + kc * 16);
        const short8v b2 = *(const short8v*)(bl2 + kc * 16);
        const short8v b3 = *(const short8v*)(bl3 + kc * 16);
        acc0 = __builtin_amdgcn_mfma_f32_32x32x16_bf16(ac, b0, acc0, 0, 0, 0);
        acc1 = __builtin_amdgcn_mfma_f32_32x32x16_bf16(ac, b1, acc1, 0, 0, 0);
        acc2 = __builtin_amdgcn_mfma_f32_32x32x16_bf16(ac, b2, acc2, 0, 0, 0);
        acc3 = __builtin_amdgcn_mfma_f32_32x32x16_bf16(ac, b3, acc3, 0, 0, 0);
        ac = an;
    }

    // inline BN2 params per lane (4 f-columns)
    float s2[4], o2[4], w2[4];
#pragma unroll
    for (int n = 0; n < 4; ++n) {
        const int f = n * 32 + r32;
        if (f < FC_) {
            const int fg = u * FC_ + f;
            const float ss = g2[fg] / sqrtf(v2[fg] + EPS_);
            s2[n] = ss;
            o2[n] = (b_fc1[fg] - m2[fg]) * ss + be2[fg];
            w2[n] = w_fc2[fg];
        } else {
            s2[n] = 0.f; o2[n] = 0.f; w2[n] = 0.f;
        }
    }
#pragma unroll
    for (int rg = 0; rg < 16; ++rg) {
        const int row = (rg & 3) + 8 * (rg >> 2) + 4 * half;
        float s = fmaxf(fmaf(acc0[rg], s2[0], o2[0]), 0.f) * w2[0];
        s = fmaf(fmaxf(fmaf(acc1[rg], s2[1], o2[1]), 0.f), w2[1], s);
        s = fmaf(fmaxf(fmaf(acc2[rg], s2[2], o2[2]), 0.f), w2[2], s);
        s = fmaf(fmaxf(fmaf(acc3[rg], s2[3], o2[3]), 0.f), w2[3], s);
        zred[wv * 32 + row][r32] = s;
    }
    __syncthreads();

    // reduce 32 lane-partials per batch row; write transposed (B,304)
    if (tid < 128) {
        float s = 0.f;
#pragma unroll
        for (int j = 0; j < 32; ++j) s += zred[tid][j];
        const float s3 = g3[u] / sqrtf(v3[u] + EPS_);
        const float o3 = (b_fc2[u] - m3[u]) * s3 + be3[u];
        zT[(size_t)(bt * 128 + tid) * 304 + u] = fmaxf(fmaf(s, s3, o3), 0.f);
    }
}

// ---------------------------------------------------------------------------
// out_k: out[b] = sigmoid( dot(zT[b,0:300], w_out) + b_out ), coalesced f4.
// ---------------------------------------------------------------------------
__global__ __launch_bounds__(64, 8)
void out_k(const float* __restrict__ zT,      // (B,304)
           const float* __restrict__ w_out,   // (U,1)
           const float* __restrict__ b_out,   // (1,)
           float* __restrict__ out)           // (B,1)
{
    const int lane = threadIdx.x;
    const int b    = blockIdx.x;
    const float4* zr = (const float4*)(zT + (size_t)b * 304);
    const float4* w4 = (const float4*)w_out;

    float s = 0.f;
    for (int i = lane; i < 75; i += 64) {
        const float4 z = zr[i], w = w4[i];
        s += z.x * w.x + z.y * w.y + z.z * w.z + z.w * w.w;
    }
#pragma unroll
    for (int o = 32; o > 0; o >>= 1) s += __shfl_xor(s, o);
    if (lane == 0)
        out[b] = 1.0f / (1.0f + __expf(-(s + b_out[0])));
}

// ---------------------------------------------------------------------------
extern "C" void kernel_launch(void* const* d_in, const int* in_sizes, int n_in,
                              void* d_out, int out_size, void* d_ws, size_t ws_size,
                              hipStream_t stream)
{
    const float* input_seq = (const float*)d_in[0];   // (B,L,4)
    const float* w_conv    = (const float*)d_in[1];
    const float* b_conv    = (const float*)d_in[2];
    const float* g1        = (const float*)d_in[3];
    const float* be1       = (const float*)d_in[4];
    const float* m1        = (const float*)d_in[5];
    const float* v1        = (const float*)d_in[6];
    const float* w_fc1     = (const float*)d_in[7];
    const float* b_fc1     = (const float*)d_in[8];
    const float* g2        = (const float*)d_in[9];
    const float* be2       = (const float*)d_in[10];
    const float* m2        = (const float*)d_in[11];
    const float* v2        = (const float*)d_in[12];
    const float* w_fc2     = (const float*)d_in[13];
    const float* b_fc2     = (const float*)d_in[14];
    const float* g3        = (const float*)d_in[15];
    const float* be3       = (const float*)d_in[16];
    const float* m3        = (const float*)d_in[17];
    const float* v3        = (const float*)d_in[18];
    const float* w_out     = (const float*)d_in[19];
    const float* b_out     = (const float*)d_in[20];

    // Workspace layout (~21.9 MB of ws):
    char* p = (char*)d_ws;
    ushort_t* pooled = (ushort_t*)p;   p += (size_t)B_ * U_ * P_ * 2;   // 21,504,000
    ushort_t* w_bf   = (ushort_t*)p;   p += 320 * 80 * 2;               //     51,200
    float*    o1g    = (float*)p;      p += 320 * 4;                    //      1,280
    float*    zT     = (float*)p;      p += (size_t)B_ * 304 * 4;       //    311,296

    pack_conv_k<<<dim3(100), 256, 0, stream>>>(
        w_conv, b_conv, g1, be1, m1, v1, w_bf, o1g);

    conv_mfma_k<<<dim3(5, B_), 896, 0, stream>>>(
        (const float4*)input_seq, w_bf, o1g, pooled);

    fc_mfma_k<<<dim3(2, U_), 256, 0, stream>>>(
        pooled, w_fc1, b_fc1, g2, be2, m2, v2, w_fc2, b_fc2,
        g3, be3, m3, v3, zT);

    out_k<<<dim3(B_), 64, 0, stream>>>(zT, w_out, b_out, (float*)d_out);
}